// Round 1
// 1378.880 us; speedup vs baseline: 1.5841x; 1.5841x over previous
//
#include <hip/hip_runtime.h>
#include <cstdint>
#include <cstddef>

#define Tt  512
#define Kk  8
#define NI  256
#define UN  256
#define G4  1024   // 4*UN

typedef unsigned short ushort_t;
typedef __attribute__((ext_vector_type(8))) short short8;
typedef __attribute__((ext_vector_type(4))) float f32x4;

__global__ void zero_ws(unsigned int* p, int n) {
    int stride = gridDim.x * blockDim.x;
    for (int i = blockIdx.x * blockDim.x + threadIdx.x; i < n; i += stride)
        p[i] = 0u;
}

__device__ __forceinline__ ushort_t f2bf(float x) {
    union { float f; unsigned int u; } v; v.f = x;
    unsigned int r = v.u + 0x7FFFu + ((v.u >> 16) & 1u);
    return (ushort_t)(r >> 16);
}

__device__ __forceinline__ float hsig(float z) {
    return fminf(1.0f, fmaxf(0.0f, fmaf(z, 0.2f, 0.5f)));
}

__device__ __forceinline__ float fast_tanh(float x) {
    float e = __expf(2.0f * x);
    return 1.0f - 2.0f * __builtin_amdgcn_rcpf(e + 1.0f);
}

// ---------------- Phase A: xw[t'][b*8+k][col] = bias + x@W (unchanged) ----------------
__global__ __launch_bounds__(256) void xw_gemm(const float* __restrict__ x,
                                               const float* __restrict__ W,
                                               const float* __restrict__ bias,
                                               float* __restrict__ xw, int t0) {
    __shared__ __align__(16) float At[16][132];
    __shared__ __align__(16) float Bt[16][132];

    const int k  = blockIdx.z;
    const int C0 = blockIdx.x * 128;
    const int R0 = blockIdx.y * 128;
    const int tid = threadIdx.x;
    const int tx = tid & 15, ty = tid >> 4;

    float acc[8][8];
#pragma unroll
    for (int i = 0; i < 8; i++)
#pragma unroll
        for (int j = 0; j < 8; j++) acc[i][j] = 0.0f;

    const int lakk = tid & 15, larl = tid >> 4;
    const int lbc  = tid & 127, lbk = tid >> 7;

    for (int kt = 0; kt < NI; kt += 16) {
#pragma unroll
        for (int ps = 0; ps < 8; ps++) {
            int rloc = larl + ps * 16;
            int r = R0 + rloc;
            int b = r & 15, tp = r >> 4;
            At[lakk][rloc] = x[(((size_t)b * Tt + (t0 + tp)) * Kk + k) * NI + kt + lakk];
        }
#pragma unroll
        for (int ps = 0; ps < 8; ps++) {
            int kkr = lbk + ps * 2;
            Bt[kkr][lbc] = W[((size_t)k * NI + kt + kkr) * G4 + C0 + lbc];
        }
        __syncthreads();
#pragma unroll
        for (int kk = 0; kk < 16; kk++) {
            const float4* Ar = (const float4*)&At[kk][ty * 8];
            const float4* Br = (const float4*)&Bt[kk][tx * 8];
            float4 a0 = Ar[0], a1 = Ar[1];
            float4 b0 = Br[0], b1 = Br[1];
            float a[8] = {a0.x, a0.y, a0.z, a0.w, a1.x, a1.y, a1.z, a1.w};
            float bb[8] = {b0.x, b0.y, b0.z, b0.w, b1.x, b1.y, b1.z, b1.w};
#pragma unroll
            for (int i = 0; i < 8; i++)
#pragma unroll
                for (int j = 0; j < 8; j++)
                    acc[i][j] = fmaf(a[i], bb[j], acc[i][j]);
        }
        __syncthreads();
    }
    float bv[8];
#pragma unroll
    for (int j = 0; j < 8; j++) bv[j] = bias[(size_t)k * G4 + C0 + tx * 8 + j];
#pragma unroll
    for (int i = 0; i < 8; i++) {
        int r = R0 + ty * 8 + i;
        int b = r & 15, tp = r >> 4;
        float* op = xw + ((size_t)tp * 128 + b * 8 + k) * G4 + C0 + tx * 8;
#pragma unroll
        for (int j = 0; j < 8; j++) op[j] = acc[i][j] + bv[j];
    }
}

// ---------------- Phase B: MFMA recurrence ----------------
// 32 wgs: k = bid&7, uq = bid>>3. Wave w holds, for EACH gate c in 0..3, the U
// columns of unit block [uq*64 + w*16, +16) -> all 4 gates of a (b,u) pair live in
// one thread's accumulators (no gact LDS exchange). Cross-wg h exchange uses
// tagged 32-bit words ((bf16<<16)|step_tag), relaxed agent atomics, parity
// double-buffered: no release fence, no flag atomic, no vmcnt(0) drain on the
// critical path. One __syncthreads per timestep (after A-frag scatter),
// hfr LDS double-buffered. Fragment LDS chunk-index XOR-swizzled (involution,
// same on write and read) to break scatter-write bank conflicts.
__global__ __launch_bounds__(256, 1) void lstm_mfma(
    const float* __restrict__ xw,        // [TC][128][1024]
    const float* __restrict__ U,         // [8][256][1024] fp32
    float* __restrict__ out,             // [16][512][8][256]
    ushort_t* __restrict__ hstate,       // [8][4096] bf16 (e = uq*1024 + b*64 + (u&63))
    float* __restrict__ cstate,          // [8*4][1024]
    unsigned int* __restrict__ hbuf,     // [2][8][4096] tagged u32
    int t0, int TC) {
    const int tid  = threadIdx.x;
    const int lane = tid & 63;
    const int w    = tid >> 6;        // wave index = unit sub-block
    const int k    = blockIdx.x & 7;
    const int uq   = blockIdx.x >> 3;
    const int l15  = lane & 15, quad = lane >> 4;

    __shared__ __align__(16) ushort_t hfr[2][4096];   // A-frag, double-buffered, swizzled

    // ---- one-time: preload B-fragments of U slice (bf16) ----
    // wave w, gate c: cols [c*256 + uq*64 + w*16, +16)
    short8 bfr[4][8];
    const size_t Ubase = (size_t)k * (256 * 1024);
#pragma unroll
    for (int c = 0; c < 4; c++) {
        const int col = c * 256 + uq * 64 + w * 16 + l15;
#pragma unroll
        for (int q = 0; q < 8; q++) {
            short8 v;
#pragma unroll
            for (int j = 0; j < 8; j++) {
                int kk = q * 32 + quad * 8 + j;
                v[j] = (short)f2bf(U[Ubase + (size_t)kk * 1024 + col]);
            }
            bfr[c][q] = v;
        }
    }

    // c-state: thread owns (b = quad*4+r, u = uq*64 + w*16 + l15)
    float cc[4];
    const size_t cbase = ((size_t)(k * 4 + uq)) * 1024 + (size_t)tid * 4;
#pragma unroll
    for (int r = 0; r < 4; r++) cc[r] = cstate[cbase + r];

    // ---- initial h scatter: hstate[k] -> hfr[0] (swizzled) ----
    {
        const ushort_t* hs = hstate + (size_t)k * 4096;
#pragma unroll
        for (int i = 0; i < 16; i++) {
            int e = tid + 256 * i;
            int b = (e >> 6) & 15;
            int u = e & 63;
            int kkg = (e >> 10) * 64 + u;
            int q = kkg >> 5, j = kkg & 7;
            int c = q * 64 + (b + 16 * ((u & 31) >> 3));
            c ^= ((c >> 4) & 3) << 1;          // swizzle (involution)
            hfr[0][c * 8 + j] = hs[e];
        }
    }
    __syncthreads();

    // prefetch xw for t=0
    const int colb = uq * 64 + w * 16 + l15;
    float xwv[4][4];
#pragma unroll
    for (int c = 0; c < 4; c++) {
#pragma unroll
        for (int r = 0; r < 4; r++) {
            int b = quad * 4 + r;
            xwv[c][r] = xw[((size_t)0 * 128 + b * 8 + k) * 1024 + c * 256 + colb];
        }
    }

    int p = 0;
#pragma unroll 1
    for (int t = 0; t < TC; t++) {
        const int g = t0 + t;

        // ---- A-frags from hfr[p] (swizzled, conflict-free 16B/lane) ----
        short8 af[8];
#pragma unroll
        for (int q = 0; q < 8; q++) {
            int c = q * 64 + (lane ^ (quad << 1));
            af[q] = *(const short8*)&hfr[p][c * 8];
        }

        // ---- z_hU = h @ Uslice via MFMA ----
        f32x4 acc[4];
        const f32x4 zv = {0.f, 0.f, 0.f, 0.f};
#pragma unroll
        for (int c = 0; c < 4; c++) acc[c] = zv;
#pragma unroll
        for (int q = 0; q < 8; q++) {
#pragma unroll
            for (int c = 0; c < 4; c++)
                acc[c] = __builtin_amdgcn_mfma_f32_16x16x32_bf16(af[q], bfr[c][q], acc[c], 0, 0, 0);
        }

        // ---- activation + c/h update, fully in-register ----
        float hn[4];
#pragma unroll
        for (int r = 0; r < 4; r++) {
            float z0 = acc[0][r] + xwv[0][r];
            float z1 = acc[1][r] + xwv[1][r];
            float z2 = acc[2][r] + xwv[2][r];
            float z3 = acc[3][r] + xwv[3][r];
            float av = fast_tanh(z0);
            float iv = hsig(z1), fv = hsig(z2), ov = hsig(z3);
            float cn = av * iv + fv * cc[r];
            cc[r] = cn;
            hn[r] = ov * fast_tanh(cn);
        }

        if (t + 1 < TC) {
            const unsigned int tg = (unsigned int)(g + 1);
            // ---- publish FIRST: tagged words, relaxed agent atomics ----
            unsigned int* dst = hbuf + ((size_t)((g + 1) & 1) * 8 + k) * 4096
                              + (size_t)uq * 1024 + w * 16 + l15;
#pragma unroll
            for (int r = 0; r < 4; r++) {
                unsigned int pv = ((unsigned int)f2bf(hn[r]) << 16) | tg;
                __hip_atomic_store(&dst[(quad * 4 + r) * 64], pv,
                                   __ATOMIC_RELAXED, __HIP_MEMORY_SCOPE_AGENT);
            }
            asm volatile("" ::: "memory");   // keep publish above the poll

            // out stores: latency overlaps the poll (drained only at the barrier)
#pragma unroll
            for (int r = 0; r < 4; r++) {
                int b = quad * 4 + r;
                out[(((size_t)b * Tt + g) * Kk + k) * UN + uq * 64 + w * 16 + l15] = hn[r];
            }

            // xw prefetch for t+1 (independent; overlaps the poll)
            float xwn[4][4];
#pragma unroll
            for (int c = 0; c < 4; c++)
#pragma unroll
                for (int r = 0; r < 4; r++) {
                    int b = quad * 4 + r;
                    xwn[c][r] = xw[((size_t)(t + 1) * 128 + b * 8 + k) * 1024 + c * 256 + colb];
                }

            // ---- poll the 16 tagged words this thread owns ----
            const unsigned int* src = hbuf + ((size_t)((g + 1) & 1) * 8 + k) * 4096;
            unsigned int vals[16];
#pragma unroll
            for (int i = 0; i < 16; i++)
                vals[i] = __hip_atomic_load(&src[tid + 256 * i],
                                            __ATOMIC_RELAXED, __HIP_MEMORY_SCOPE_AGENT);
            for (;;) {
                bool ok = true;
#pragma unroll
                for (int i = 0; i < 16; i++) ok &= ((vals[i] & 0xFFFFu) == tg);
                if (ok) break;
#pragma unroll
                for (int i = 0; i < 16; i++)
                    vals[i] = __hip_atomic_load(&src[tid + 256 * i],
                                                __ATOMIC_RELAXED, __HIP_MEMORY_SCOPE_AGENT);
            }

            // ---- scatter h_{t+1} -> hfr[p^1] (swizzled) ----
            const int pn = p ^ 1;
#pragma unroll
            for (int i = 0; i < 16; i++) {
                int e = tid + 256 * i;
                int b = (e >> 6) & 15;
                int u = e & 63;
                int kkg = (e >> 10) * 64 + u;
                int q = kkg >> 5, j = kkg & 7;
                int c = q * 64 + (b + 16 * ((u & 31) >> 3));
                c ^= ((c >> 4) & 3) << 1;
                hfr[pn][c * 8 + j] = (ushort_t)(vals[i] >> 16);
            }
            __syncthreads();                  // the ONLY barrier per step
            p = pn;
#pragma unroll
            for (int c = 0; c < 4; c++)
#pragma unroll
                for (int r = 0; r < 4; r++) xwv[c][r] = xwn[c][r];
        } else {
            // chunk end: out + persist state
#pragma unroll
            for (int r = 0; r < 4; r++) {
                int b = quad * 4 + r;
                out[(((size_t)b * Tt + g) * Kk + k) * UN + uq * 64 + w * 16 + l15] = hn[r];
                hstate[(size_t)k * 4096 + (size_t)uq * 1024 + b * 64 + w * 16 + l15] = f2bf(hn[r]);
                cstate[cbase + r] = cc[r];
            }
        }
    }
}

extern "C" void kernel_launch(void* const* d_in, const int* in_sizes, int n_in,
                              void* d_out, int out_size, void* d_ws, size_t ws_size,
                              hipStream_t stream) {
    const float* x    = (const float*)d_in[0];
    const float* W    = (const float*)d_in[1];
    const float* U    = (const float*)d_in[2];
    const float* bias = (const float*)d_in[3];
    float* out = (float*)d_out;

    // tail state: cstate 128KB | hstate 64KB | hbuf(tagged u32) 256KB
    const size_t TAIL = 131072 + 65536 + 262144;  // 458752 B
    int TC = 16;
    const int cands[6] = {512, 256, 128, 64, 32, 16};
    for (int ci = 0; ci < 6; ci++) {
        size_t need = (size_t)cands[ci] * 128 * 1024 * 4 + TAIL;
        if (need <= ws_size) { TC = cands[ci]; break; }
    }

    float* xw = (float*)d_ws;
    char* p = (char*)d_ws + (size_t)TC * 128 * 1024 * 4;
    float*        cstate = (float*)p;         p += 131072;
    ushort_t*     hstate = (ushort_t*)p;      p += 65536;
    unsigned int* hbuf   = (unsigned int*)p;

    zero_ws<<<dim3(128), dim3(256), 0, stream>>>((unsigned int*)cstate,
                                                 (int)(TAIL / 4));

    for (int t0 = 0; t0 < Tt; t0 += TC) {
        xw_gemm<<<dim3(G4 / 128, TC * 16 / 128, Kk), dim3(256), 0, stream>>>(
            x, W, bias, xw, t0);
        lstm_mfma<<<dim3(32), dim3(256), 0, stream>>>(
            xw, U, out, hstate, cstate, hbuf, t0, TC);
    }
}